// Round 1
// baseline (292.247 us; speedup 1.0000x reference)
//
#include <hip/hip_runtime.h>

// Problem constants (PointPillarScatter_Seg): B=4, P_PER=20000, C=64, NY=NX=512
constexpr int C_CH = 64;
constexpr int NY_D = 512;
constexpr int NX_D = 512;
constexpr int CELLS_PER_BATCH = NY_D * NX_D;  // 262144

// ---------------------------------------------------------------------------
// Kernel 1: fill the pillar-index canvas with -1 (empty cell sentinel).
// 1M int32 = 4 MB, written as int4 -> 262144 threads.
// ---------------------------------------------------------------------------
__global__ void fill_idx(int4* __restrict__ canvas4, int n4) {
    int t = blockIdx.x * blockDim.x + threadIdx.x;
    if (t < n4) canvas4[t] = make_int4(-1, -1, -1, -1);
}

// ---------------------------------------------------------------------------
// Kernel 2: scatter pillar id p into canvas[b, y, x].
// coords[p] = (b, z, y, x) int32. Indices are unique per batch -> no races.
// ---------------------------------------------------------------------------
__global__ void scatter_idx(const int4* __restrict__ coords,
                            int* __restrict__ canvas, int P) {
    int p = blockIdx.x * blockDim.x + threadIdx.x;
    if (p < P) {
        int4 c = coords[p];  // c.x = batch, c.y = z(=0), c.z = y, c.w = x
        canvas[c.x * CELLS_PER_BATCH + c.z * NX_D + c.w] = p;
    }
}

// ---------------------------------------------------------------------------
// Kernel 3: gather. One thread owns 4 consecutive x cells for ALL 64 channels.
// Reads the 4 pillar ids once (int4), then per 4-channel chunk loads float4
// feature fragments and writes 4 coalesced float4 output rows (4x4 register
// transpose). Every feature row (256 B) is read exactly once, contiguously.
// Output: out[b, c, y, x] = b*(C*NY*NX) + c*(NY*NX) + y*NX + x.
// ---------------------------------------------------------------------------
__global__ void gather_out(const float* __restrict__ feat,
                           const int* __restrict__ canvas,
                           float* __restrict__ out) {
    int t = blockIdx.x * blockDim.x + threadIdx.x;  // [0, B*NY*NX/4)
    int x0 = (t & (NX_D / 4 - 1)) << 2;          // 0..508, step 4
    int y  = (t >> 7) & (NY_D - 1);              // NX/4 = 128 -> shift 7
    int b  = t >> 16;                            // / (128*512)

    int cell = b * CELLS_PER_BATCH + y * NX_D + x0;
    int4 idx = *reinterpret_cast<const int4*>(canvas + cell);

    float* op = out + (size_t)b * (C_CH * CELLS_PER_BATCH) + y * NX_D + x0;

    const float4 z4 = make_float4(0.f, 0.f, 0.f, 0.f);
    const float* ra = feat + (size_t)idx.x * C_CH;
    const float* rb = feat + (size_t)idx.y * C_CH;
    const float* rc = feat + (size_t)idx.z * C_CH;
    const float* rd = feat + (size_t)idx.w * C_CH;

#pragma unroll 4
    for (int c0 = 0; c0 < C_CH; c0 += 4) {
        float4 fa = (idx.x >= 0) ? *reinterpret_cast<const float4*>(ra + c0) : z4;
        float4 fb = (idx.y >= 0) ? *reinterpret_cast<const float4*>(rb + c0) : z4;
        float4 fc = (idx.z >= 0) ? *reinterpret_cast<const float4*>(rc + c0) : z4;
        float4 fd = (idx.w >= 0) ? *reinterpret_cast<const float4*>(rd + c0) : z4;

        *reinterpret_cast<float4*>(op + (size_t)(c0 + 0) * CELLS_PER_BATCH) =
            make_float4(fa.x, fb.x, fc.x, fd.x);
        *reinterpret_cast<float4*>(op + (size_t)(c0 + 1) * CELLS_PER_BATCH) =
            make_float4(fa.y, fb.y, fc.y, fd.y);
        *reinterpret_cast<float4*>(op + (size_t)(c0 + 2) * CELLS_PER_BATCH) =
            make_float4(fa.z, fb.z, fc.z, fd.z);
        *reinterpret_cast<float4*>(op + (size_t)(c0 + 3) * CELLS_PER_BATCH) =
            make_float4(fa.w, fb.w, fc.w, fd.w);
    }
}

// ---------------------------------------------------------------------------
extern "C" void kernel_launch(void* const* d_in, const int* in_sizes, int n_in,
                              void* d_out, int out_size, void* d_ws, size_t ws_size,
                              hipStream_t stream) {
    const float* feat  = (const float*)d_in[0];          // [P, 64] fp32
    const int*  coords = (const int*)d_in[1];            // [P, 4] int32
    float* out = (float*)d_out;                          // [B, 64, 512, 512] fp32

    const int P = in_sizes[1] / 4;                       // 80000
    const int B = out_size / (C_CH * CELLS_PER_BATCH);   // 4

    int* canvas = (int*)d_ws;                            // B*NY*NX int32 = 4 MB
    const int ncells = B * CELLS_PER_BATCH;              // 1048576

    // 1) fill index canvas with -1
    {
        int n4 = ncells / 4;
        fill_idx<<<(n4 + 255) / 256, 256, 0, stream>>>((int4*)canvas, n4);
    }
    // 2) scatter pillar ids
    scatter_idx<<<(P + 255) / 256, 256, 0, stream>>>(
        (const int4*)coords, canvas, P);
    // 3) gather + write output (coalesced)
    {
        int nt = ncells / 4;                             // 262144 threads
        gather_out<<<(nt + 255) / 256, 256, 0, stream>>>(feat, canvas, out);
    }
}